// Round 10
// baseline (82.774 us; speedup 1.0000x reference)
//
#include <hip/hip_runtime.h>
#include <hip/hip_bf16.h>

#define N_IN    256
#define N_HID   128
#define N_ELEM  5
#define NBLK    256                 // 256 blocks x 4 waves = 1024 independent waves
#define NWAVE   1024
#define ESTRIDE 66560               // per-expert image: 65536 frag + 1024 params

typedef __attribute__((ext_vector_type(8))) short  short8;
typedef __attribute__((ext_vector_type(4))) short  short4v;
typedef __attribute__((ext_vector_type(4))) float  float4v;

__device__ __forceinline__ int expert_of(int z) {
    return (z == 1) ? 0 : (z == 6) ? 1 : (z == 7) ? 2 : (z == 8) ? 3 : 4;
}
__device__ __forceinline__ short f2bf(float f) {
    union { float f; unsigned u; } c; c.f = f;
    unsigned r = (c.u + 0x7fffu + ((c.u >> 16) & 1u)) >> 16;
    return (short)r;
}

// ---------------- fused prep (swizzled W1 frag image + params) + histogram ----
// frag[slot=n*8+kk][lane] (16B) = bf16x8 of W1[e][n*16+(lane&15)][kk*32+(lane>>4)*8..]
// params @65536: b1[128] fp32, then w2[128] fp32.
__global__ void prep_hist_kernel(const float* __restrict__ W1, const float* __restrict__ B1f,
                                 const float* __restrict__ W2f, char* __restrict__ W1s,
                                 const int* __restrict__ z, int n, int* __restrict__ counts) {
    if (blockIdx.x < 85) {
        int idx = blockIdx.x * 256 + threadIdx.x;
        if (idx < 20480) {
            int e = idx >> 12, rem = idx & 4095;
            int slot = rem >> 6, lane = rem & 63;
            int nrow = (slot >> 3) * 16 + (lane & 15);
            int k0 = (slot & 7) * 32 + (lane >> 4) * 8;
            const float* src = W1 + ((size_t)(e * N_HID + nrow) * N_IN + k0);
            float4v f0 = *(const float4v*)src;
            float4v f1 = *(const float4v*)(src + 4);
            short8 s;
            s[0] = f2bf(f0[0]); s[1] = f2bf(f0[1]); s[2] = f2bf(f0[2]); s[3] = f2bf(f0[3]);
            s[4] = f2bf(f1[0]); s[5] = f2bf(f1[1]); s[6] = f2bf(f1[2]); s[7] = f2bf(f1[3]);
            *(short8*)(W1s + (size_t)e * ESTRIDE + slot * 1024 + lane * 16) = s;
        } else {
            int idx2 = idx - 20480;              // < 1280
            int e = idx2 >> 8, i = idx2 & 255;
            float* dst = (float*)(W1s + (size_t)e * ESTRIDE + 65536);
            if (i < 128) dst[i] = B1f[e * N_HID + i];
            else         dst[128 + (i - 128)] = W2f[e * N_HID + (i - 128)];
        }
        return;
    }
    __shared__ int cnt[N_ELEM];
    if (threadIdx.x < N_ELEM) cnt[threadIdx.x] = 0;
    __syncthreads();
    int i = (blockIdx.x - 85) * blockDim.x + threadIdx.x;
    if (i < n) atomicAdd(&cnt[expert_of(z[i])], 1);
    __syncthreads();
    if (threadIdx.x < N_ELEM && cnt[threadIdx.x]) atomicAdd(&counts[threadIdx.x], cnt[threadIdx.x]);
}

// ---------------- scatter (computes prefix from counts in-block) ---------------
__global__ void scatter_kernel(const int* __restrict__ z, int n,
                               const int* __restrict__ counts,
                               int* __restrict__ cursorRel, int* __restrict__ perm) {
    __shared__ int cnt[N_ELEM], cur[N_ELEM], base[N_ELEM];
    int tid = threadIdx.x;
    if (tid < N_ELEM) { cnt[tid] = 0; cur[tid] = 0; }
    __syncthreads();
    int i = blockIdx.x * blockDim.x + tid;
    int e = -1;
    if (i < n) { e = expert_of(z[i]); atomicAdd(&cnt[e], 1); }
    __syncthreads();
    if (tid < N_ELEM) {
        int pfx = 0;
        for (int k = 0; k < tid; ++k) pfx += counts[k];
        base[tid] = cnt[tid] ? pfx + atomicAdd(&cursorRel[tid], cnt[tid]) : 0;
    }
    __syncthreads();
    if (e >= 0) {
        int r = atomicAdd(&cur[e], 1);
        perm[base[e] + r] = i;
    }
}

// ---------------- mlp: 1024 independent waves, register-staged A, zero LDS -----
// Wave owns contiguous 16-atom subtiles (expert-sorted). Per subtile:
//   A(t) regs already in flight; cvt -> bf16; issue A(t+1); 64 MFMA vs
//   register-resident bfrag[8][8] (256 VGPR, reloaded only on expert change);
//   silu+dot+butterfly in regs; scattered 4B store. No barriers, no LDS.
__launch_bounds__(256, 1)
__global__ void mlp_kernel(const float* __restrict__ X, const char* __restrict__ W1s,
                           const float* __restrict__ B2f, const int* __restrict__ perm,
                           const int* __restrict__ counts, float* __restrict__ out) {
    int lane = threadIdx.x & 63;
    int w    = threadIdx.x >> 6;
    int am   = lane & 15, g = lane >> 4;

    int c0 = counts[0], c1 = counts[1], c2 = counts[2], c3 = counts[3], c4 = counts[4];
    int so1 = c0, so2 = c0 + c1, so3 = so2 + c2, so4 = so3 + c3;
    int tp1 = (c0 + 15) >> 4;
    int tp2 = tp1 + ((c1 + 15) >> 4);
    int tp3 = tp2 + ((c2 + 15) >> 4);
    int tp4 = tp3 + ((c3 + 15) >> 4);
    int nSub = tp4 + ((c4 + 15) >> 4);

    int wid = blockIdx.x * 4 + w;
    int q = nSub / NWAVE, r = nSub % NWAVE;
    int s0 = wid * q + min(wid, r);
    int s1 = s0 + q + (wid < r ? 1 : 0);
    if (s0 >= s1) return;

    // subtile s -> expert, atom range
#define SUBINFO(s_, e_, rs_, rows_) do {                                        \
    e_ = ((s_) >= tp1) + ((s_) >= tp2) + ((s_) >= tp3) + ((s_) >= tp4);         \
    int soE_ = (e_ == 0) ? 0 : (e_ == 1) ? so1 : (e_ == 2) ? so2                \
             : (e_ == 3) ? so3 : so4;                                           \
    int tpE_ = (e_ == 0) ? 0 : (e_ == 1) ? tp1 : (e_ == 2) ? tp2                \
             : (e_ == 3) ? tp3 : tp4;                                           \
    int ctE_ = (e_ == 0) ? c0 : (e_ == 1) ? c1 : (e_ == 2) ? c2                 \
             : (e_ == 3) ? c3 : c4;                                             \
    rs_ = soE_ + ((s_) - tpE_) * 16;                                            \
    rows_ = min(16, soE_ + ctE_ - rs_);                                         \
} while (0)

    short8 bfrag[8][8];               // 256 VGPR: full 128-hidden B for one expert
    float  b1c[8], w2c[8], b2v = 0.0f;
#define LOADB(e_) do {                                                          \
    const char* img_ = W1s + (size_t)(e_) * ESTRIDE;                            \
    const float* prm_ = (const float*)(img_ + 65536);                           \
    _Pragma("unroll")                                                           \
    for (int n_ = 0; n_ < 8; ++n_) {                                            \
        _Pragma("unroll")                                                       \
        for (int kk_ = 0; kk_ < 8; ++kk_)                                       \
            bfrag[n_][kk_] = *(const short8*)(img_ + (n_ * 8 + kk_) * 1024 + lane * 16); \
        b1c[n_] = prm_[n_ * 16 + am];                                           \
        w2c[n_] = prm_[128 + n_ * 16 + am];                                     \
    }                                                                           \
    b2v = B2f[e_];                                                              \
} while (0)

#define ISSUEA(gid_, raw_) do {                                                 \
    const float* base_ = X + ((size_t)(unsigned)(gid_) << 8) + g * 8;           \
    _Pragma("unroll")                                                           \
    for (int kk_ = 0; kk_ < 8; ++kk_) {                                         \
        raw_[2 * kk_]     = *(const float4v*)(base_ + kk_ * 32);                \
        raw_[2 * kk_ + 1] = *(const float4v*)(base_ + kk_ * 32 + 4);            \
    }                                                                           \
} while (0)

    // ---- prologue
    int eC, rsC, rowsC;
    SUBINFO(s0, eC, rsC, rowsC);
    int eLoaded = eC;
    LOADB(eC);
    int gidC = perm[rsC + min(am, rowsC - 1)];
    float4v rawA[16];
    ISSUEA(gidC, rawA);
    int eN = eC, rowsN = rowsC, gidN = gidC;
    if (s0 + 1 < s1) {
        int rsN_;
        SUBINFO(s0 + 1, eN, rsN_, rowsN);
        gidN = perm[rsN_ + min(am, rowsN - 1)];
    }

    for (int s = s0; s < s1; ++s) {
        // prefetch gid two ahead
        int eNN = eN, rowsNN = rowsN, gidNN = gidN;
        if (s + 2 < s1) {
            int rsNN_;
            SUBINFO(s + 2, eNN, rsNN_, rowsNN);
            gidNN = perm[rsNN_ + min(am, rowsNN - 1)];
        }
        if (eC != eLoaded) { LOADB(eC); eLoaded = eC; }

        // cvt A(s): compiler inserts the vmcnt wait for rawA here
        short8 abf[8];
#pragma unroll
        for (int kk = 0; kk < 8; ++kk) {
            union { __hip_bfloat162 h[4]; short8 v; } u;
            u.h[0] = __float22bfloat162_rn({rawA[2 * kk][0], rawA[2 * kk][1]});
            u.h[1] = __float22bfloat162_rn({rawA[2 * kk][2], rawA[2 * kk][3]});
            u.h[2] = __float22bfloat162_rn({rawA[2 * kk + 1][0], rawA[2 * kk + 1][1]});
            u.h[3] = __float22bfloat162_rn({rawA[2 * kk + 1][2], rawA[2 * kk + 1][3]});
            abf[kk] = u.v;
        }
        // issue A(s+1) into the freed raw regs
        if (s + 1 < s1) ISSUEA(gidN, rawA);

        // 64 MFMAs: 16 atoms x 128 hidden x K=256
        float4v acc[8] = {};
#pragma unroll
        for (int kk = 0; kk < 8; ++kk)
#pragma unroll
            for (int n = 0; n < 8; ++n)
                acc[n] = __builtin_amdgcn_mfma_f32_16x16x32_bf16(abf[kk], bfrag[n][kk], acc[n], 0, 0, 0);

        // epilogue: bias + silu + dot(w2) per lane (8 cols), butterfly over 16 cols
        float pv0 = 0, pv1 = 0, pv2 = 0, pv3 = 0;
#pragma unroll
        for (int n = 0; n < 8; ++n) {
            float v0 = acc[n][0] + b1c[n]; v0 = v0 / (1.0f + __expf(-v0));
            float v1 = acc[n][1] + b1c[n]; v1 = v1 / (1.0f + __expf(-v1));
            float v2 = acc[n][2] + b1c[n]; v2 = v2 / (1.0f + __expf(-v2));
            float v3 = acc[n][3] + b1c[n]; v3 = v3 / (1.0f + __expf(-v3));
            pv0 += v0 * w2c[n]; pv1 += v1 * w2c[n];
            pv2 += v2 * w2c[n]; pv3 += v3 * w2c[n];
        }
#pragma unroll
        for (int sh = 1; sh <= 8; sh <<= 1) {
            pv0 += __shfl_xor(pv0, sh, 64);
            pv1 += __shfl_xor(pv1, sh, 64);
            pv2 += __shfl_xor(pv2, sh, 64);
            pv3 += __shfl_xor(pv3, sh, 64);
        }
        // C layout: row = g*4 + reg; lanes am<4 store rows g*4+am
        float val = (am == 0) ? pv0 : (am == 1) ? pv1 : (am == 2) ? pv2 : pv3;
        int tgt = __shfl(gidC, g * 4 + am, 64);
        if (am < 4 && g * 4 + am < rowsC) out[tgt] = val + b2v;

        // shift pipeline state
        eC = eN; rowsC = rowsN; gidC = gidN;
        eN = eNN; rowsN = rowsNN; gidN = gidNN;
    }
#undef SUBINFO
#undef LOADB
#undef ISSUEA
}

// ---------------- launch -------------------------------------------------------
extern "C" void kernel_launch(void* const* d_in, const int* in_sizes, int n_in,
                              void* d_out, int out_size, void* d_ws, size_t ws_size,
                              hipStream_t stream) {
    const int*   z  = (const int*)  d_in[0];
    const float* X  = (const float*)d_in[1];
    const float* W1 = (const float*)d_in[2];
    const float* B1 = (const float*)d_in[3];
    const float* W2 = (const float*)d_in[4];
    const float* B2 = (const float*)d_in[5];
    float* out = (float*)d_out;
    int nAtoms = in_sizes[0];

    char* ws = (char*)d_ws;
    size_t off = 0;
    char* W1s      = ws + off;         off += (size_t)N_ELEM * ESTRIDE;  // 332800
    int* perm      = (int*)(ws + off); off += (size_t)nAtoms * 4;
    int* counts    = (int*)(ws + off); off += 32;
    int* cursorRel = (int*)(ws + off); off += 32;

    hipMemsetAsync(counts, 0, 64, stream);   // counts + cursorRel

    int hb = (nAtoms + 255) / 256;
    prep_hist_kernel<<<85 + hb, 256, 0, stream>>>(W1, B1, W2, W1s, z, nAtoms, counts);
    scatter_kernel<<<hb, 256, 0, stream>>>(z, nAtoms, counts, cursorRel, perm);
    mlp_kernel<<<NBLK, 256, 0, stream>>>(X, W1s, B2, perm, counts, out);
}

// Round 14
// 74.357 us; speedup vs baseline: 1.1132x; 1.1132x over previous
//
#include <hip/hip_runtime.h>
#include <hip/hip_bf16.h>

#define N_IN    256
#define N_HID   128
#define N_ELEM  5
#define NBLK    512                 // blocks; 2 per CU (65.5KB LDS each)
#define ESTRIDE 66560               // per-expert image: 65536 frag + 1024 params

typedef __attribute__((ext_vector_type(8))) short  short8;
typedef __attribute__((ext_vector_type(4))) short  short4v;
typedef __attribute__((ext_vector_type(4))) float  float4v;

__device__ __forceinline__ int expert_of(int z) {
    return (z == 1) ? 0 : (z == 6) ? 1 : (z == 7) ? 2 : (z == 8) ? 3 : 4;
}
__device__ __forceinline__ short f2bf(float f) {
    union { float f; unsigned u; } c; c.f = f;
    unsigned r = (c.u + 0x7fffu + ((c.u >> 16) & 1u)) >> 16;
    return (short)r;
}

#define AS3 __attribute__((address_space(3)))
#define GLOAD_LDS16(gsrc, ldst) \
    __builtin_amdgcn_global_load_lds((const __attribute__((address_space(1))) void*)(gsrc), \
                                     (AS3 void*)(ldst), 16, 0, 0)
__device__ __forceinline__ unsigned lds_off(const void* p) {
    return (unsigned)(size_t)(AS3 const char*)p;
}

#define DSR128(dst, a) asm volatile("ds_read_b128 %0, %1" : "=v"(dst) : "v"(a))
#define LGKM0 do { asm volatile("s_waitcnt lgkmcnt(0)" ::: "memory"); \
                   __builtin_amdgcn_sched_barrier(0); } while (0)
#define WAITV0 do { asm volatile("s_waitcnt vmcnt(0)" ::: "memory"); \
                    __builtin_amdgcn_sched_barrier(0); } while (0)

// ---------------- fused prep (swizzled W1 frag image + params) + histogram ----
// frag[slot=n*8+kk][lane] (16B) = bf16x8 of W1[e][n*16+(lane&15)][kk*32+(lane>>4)*8..]
// params @65536: b1[128] fp32, then w2[128] fp32.  (proven in R9/R10)
__global__ void prep_hist_kernel(const float* __restrict__ W1, const float* __restrict__ B1f,
                                 const float* __restrict__ W2f, char* __restrict__ W1s,
                                 const int* __restrict__ z, int n, int* __restrict__ counts) {
    if (blockIdx.x < 85) {
        int idx = blockIdx.x * 256 + threadIdx.x;
        if (idx < 20480) {
            int e = idx >> 12, rem = idx & 4095;
            int slot = rem >> 6, lane = rem & 63;
            int nrow = (slot >> 3) * 16 + (lane & 15);
            int k0 = (slot & 7) * 32 + (lane >> 4) * 8;
            const float* src = W1 + ((size_t)(e * N_HID + nrow) * N_IN + k0);
            float4v f0 = *(const float4v*)src;
            float4v f1 = *(const float4v*)(src + 4);
            short8 s;
            s[0] = f2bf(f0[0]); s[1] = f2bf(f0[1]); s[2] = f2bf(f0[2]); s[3] = f2bf(f0[3]);
            s[4] = f2bf(f1[0]); s[5] = f2bf(f1[1]); s[6] = f2bf(f1[2]); s[7] = f2bf(f1[3]);
            *(short8*)(W1s + (size_t)e * ESTRIDE + slot * 1024 + lane * 16) = s;
        } else {
            int idx2 = idx - 20480;              // < 1280
            int e = idx2 >> 8, i = idx2 & 255;
            float* dst = (float*)(W1s + (size_t)e * ESTRIDE + 65536);
            if (i < 128) dst[i] = B1f[e * N_HID + i];
            else         dst[128 + (i - 128)] = W2f[e * N_HID + (i - 128)];
        }
        return;
    }
    __shared__ int cnt[N_ELEM];
    if (threadIdx.x < N_ELEM) cnt[threadIdx.x] = 0;
    __syncthreads();
    int i = (blockIdx.x - 85) * blockDim.x + threadIdx.x;
    if (i < n) atomicAdd(&cnt[expert_of(z[i])], 1);
    __syncthreads();
    if (threadIdx.x < N_ELEM && cnt[threadIdx.x]) atomicAdd(&counts[threadIdx.x], cnt[threadIdx.x]);
}

// ---------------- scatter (computes prefix from counts in-block) ---------------
__global__ void scatter_kernel(const int* __restrict__ z, int n,
                               const int* __restrict__ counts,
                               int* __restrict__ cursorRel, int* __restrict__ perm) {
    __shared__ int cnt[N_ELEM], cur[N_ELEM], base[N_ELEM];
    int tid = threadIdx.x;
    if (tid < N_ELEM) { cnt[tid] = 0; cur[tid] = 0; }
    __syncthreads();
    int i = blockIdx.x * blockDim.x + tid;
    int e = -1;
    if (i < n) { e = expert_of(z[i]); atomicAdd(&cnt[e], 1); }
    __syncthreads();
    if (tid < N_ELEM) {
        int pfx = 0;
        for (int k = 0; k < tid; ++k) pfx += counts[k];
        base[tid] = cnt[tid] ? pfx + atomicAdd(&cursorRel[tid], cnt[tid]) : 0;
    }
    __syncthreads();
    if (e >= 0) {
        int r = atomicAdd(&cur[e], 1);
        perm[base[e] + r] = i;
    }
}

// ---------------- mlp: expert-uniform blocks, shared 64KB B, independent waves -
// Blocks are partitioned across experts proportionally to subtile counts (pure
// integer math from counts, identical in every block). Per block: all 4 waves
// cooperatively DMA the expert's FULL 64KB image (16 slots each), vmcnt(0) +
// ONE __syncthreads (before any divergence), then each wave independently runs
// the R10 pipeline: reg-staged A (compiler-managed waits), asm ds_read_b128
// B-frags + lgkmcnt(0)+sched_barrier per kk (rule 18), in-reg epilogue.
__launch_bounds__(256, 2)
__global__ void mlp_kernel(const float* __restrict__ X, const char* __restrict__ W1s,
                           const float* __restrict__ B2f, const int* __restrict__ perm,
                           const int* __restrict__ counts, float* __restrict__ out) {
    __shared__ char Bs[65536];              // one expert's full fragment image

    int lane = threadIdx.x & 63;
    int w    = threadIdx.x >> 6;
    int am   = lane & 15, g = lane >> 4;

    // ---- per-expert tables (uniform across all blocks)
    int cntv[N_ELEM], so[N_ELEM], ns[N_ELEM];
    int nSub = 0, acc0 = 0;
#pragma unroll
    for (int e = 0; e < N_ELEM; ++e) {
        cntv[e] = counts[e];
        so[e] = acc0; acc0 += cntv[e];
        ns[e] = (cntv[e] + 15) >> 4;
        nSub += ns[e];
    }
    // proportional block allocation (largest-floor + round-robin extras)
    int blk[N_ELEM], tot = 0;
#pragma unroll
    for (int e = 0; e < N_ELEM; ++e) {
        blk[e] = (int)(((long long)NBLK * ns[e]) / nSub);
        tot += blk[e];
    }
    int rem = NBLK - tot;                    // 0..4
#pragma unroll
    for (int e = 0; e < N_ELEM; ++e)
        if (rem > 0 && ns[e] > 0) { blk[e]++; rem--; }
    while (rem > 0) { blk[0]++; rem--; }     // safety (unreachable in practice)
#pragma unroll
    for (int e = 0; e < N_ELEM; ++e)
        if (ns[e] > 0 && blk[e] == 0) {      // safety: guarantee >=1 block
            int m = 0;
            for (int j = 1; j < N_ELEM; ++j) if (blk[j] > blk[m]) m = j;
            blk[m]--; blk[e]++;
        }
    int bp1 = blk[0], bp2 = bp1 + blk[1], bp3 = bp2 + blk[2], bp4 = bp3 + blk[3];

    int b = blockIdx.x;
    int e = (b >= bp1) + (b >= bp2) + (b >= bp3) + (b >= bp4);
    int bloc = b - ((e == 0) ? 0 : (e == 1) ? bp1 : (e == 2) ? bp2 : (e == 3) ? bp3 : bp4);
    int BE = blk[e], NE = ns[e];
    int soE = so[e], ctE = cntv[e];

    // ---- cooperative B image load: ALL waves, before any divergent exit
    const char* img = W1s + (size_t)e * ESTRIDE;
    {
        const char* wsrc = img + w * 16384 + lane * 16;
        char* wdst = Bs + w * 16384;
#pragma unroll
        for (int i = 0; i < 16; ++i)
            GLOAD_LDS16(wsrc + i * 1024, wdst + i * 1024);
    }
    WAITV0;
    __syncthreads();                         // B image complete for all waves

    // ---- per-wave subtile range (expert-local indices)
    int qe = (BE > 0) ? NE / BE : 0, re = (BE > 0) ? NE % BE : 0;
    int tb0 = bloc * qe + min(bloc, re);
    int tb1 = tb0 + qe + (bloc < re ? 1 : 0);
    int L = tb1 - tb0;
    int qw = L >> 2, rw = L & 3;
    int s0 = tb0 + w * qw + min(w, rw);
    int s1 = s0 + qw + (w < rw ? 1 : 0);
    if (s0 >= s1) return;                    // after the one barrier: safe

    unsigned BOFF = lds_off(Bs);
    int lastA = soE + ctE - 1;

    // params (tiny, L2-resident)
    const float* prm = (const float*)(img + 65536);
    float b1c[8], w2c[8];
#pragma unroll
    for (int n = 0; n < 8; ++n) {
        b1c[n] = prm[n * 16 + am];
        w2c[n] = prm[128 + n * 16 + am];
    }
    float b2v = B2f[e];

#define ROWSOF(s_) min(16, ctE - (s_) * 16)
#define GIDOF(s_, rows_) perm[min(soE + (s_) * 16 + am, lastA)]

#define ISSUEA(gid_, raw_) do {                                                 \
    const float* base_ = X + ((size_t)(unsigned)(gid_) << 8) + g * 8;           \
    _Pragma("unroll")                                                           \
    for (int kk_ = 0; kk_ < 8; ++kk_) {                                         \
        raw_[2 * kk_]     = *(const float4v*)(base_ + kk_ * 32);                \
        raw_[2 * kk_ + 1] = *(const float4v*)(base_ + kk_ * 32 + 4);            \
    }                                                                           \
} while (0)

    // ---- prologue
    int rowsC = ROWSOF(s0);
    int gidC = GIDOF(s0, rowsC);
    float4v rawA[16];
    ISSUEA(gidC, rawA);
    int rowsN = rowsC, gidN = gidC;
    if (s0 + 1 < s1) { rowsN = ROWSOF(s0 + 1); gidN = GIDOF(s0 + 1, rowsN); }

    for (int s = s0; s < s1; ++s) {
        int rowsNN = rowsN, gidNN = gidN;
        if (s + 2 < s1) { rowsNN = ROWSOF(s + 2); gidNN = GIDOF(s + 2, rowsNN); }

        // cvt A(s): compiler inserts its own vmcnt wait for rawA
        short8 abf[8];
#pragma unroll
        for (int kk = 0; kk < 8; ++kk) {
            union { __hip_bfloat162 h[4]; short8 v; } u;
            u.h[0] = __float22bfloat162_rn({rawA[2 * kk][0], rawA[2 * kk][1]});
            u.h[1] = __float22bfloat162_rn({rawA[2 * kk][2], rawA[2 * kk][3]});
            u.h[2] = __float22bfloat162_rn({rawA[2 * kk + 1][0], rawA[2 * kk + 1][1]});
            u.h[3] = __float22bfloat162_rn({rawA[2 * kk + 1][2], rawA[2 * kk + 1][3]});
            abf[kk] = u.v;
        }
        if (s + 1 < s1) ISSUEA(gidN, rawA);  // next tile's loads in flight

        // K-loop: B-frags from shared LDS image (never rewritten -> race-free)
        float4v acc[8] = {};
        short8 bpre[8];
#pragma unroll
        for (int kk = 0; kk < 8; ++kk) {
#pragma unroll
            for (int n = 0; n < 8; ++n)
                DSR128(bpre[n], BOFF + (unsigned)((n * 8 + kk) * 1024 + lane * 16));
            LGKM0;
#pragma unroll
            for (int n = 0; n < 8; ++n)
                acc[n] = __builtin_amdgcn_mfma_f32_16x16x32_bf16(
                    abf[kk], bpre[n], acc[n], 0, 0, 0);
        }

        // epilogue: bias + silu + dot(w2), butterfly over 16 am-lanes
        float pv0 = 0, pv1 = 0, pv2 = 0, pv3 = 0;
#pragma unroll
        for (int n = 0; n < 8; ++n) {
            float v0 = acc[n][0] + b1c[n]; v0 = v0 / (1.0f + __expf(-v0));
            float v1 = acc[n][1] + b1c[n]; v1 = v1 / (1.0f + __expf(-v1));
            float v2 = acc[n][2] + b1c[n]; v2 = v2 / (1.0f + __expf(-v2));
            float v3 = acc[n][3] + b1c[n]; v3 = v3 / (1.0f + __expf(-v3));
            pv0 += v0 * w2c[n]; pv1 += v1 * w2c[n];
            pv2 += v2 * w2c[n]; pv3 += v3 * w2c[n];
        }
#pragma unroll
        for (int sh = 1; sh <= 8; sh <<= 1) {
            pv0 += __shfl_xor(pv0, sh, 64);
            pv1 += __shfl_xor(pv1, sh, 64);
            pv2 += __shfl_xor(pv2, sh, 64);
            pv3 += __shfl_xor(pv3, sh, 64);
        }
        float val = (am == 0) ? pv0 : (am == 1) ? pv1 : (am == 2) ? pv2 : pv3;
        int tgt = __shfl(gidC, g * 4 + am, 64);
        if (am < 4 && g * 4 + am < rowsC) out[tgt] = val + b2v;

        rowsC = rowsN; gidC = gidN;
        rowsN = rowsNN; gidN = gidNN;
    }
#undef ROWSOF
#undef GIDOF
#undef ISSUEA
}

// ---------------- launch -------------------------------------------------------
extern "C" void kernel_launch(void* const* d_in, const int* in_sizes, int n_in,
                              void* d_out, int out_size, void* d_ws, size_t ws_size,
                              hipStream_t stream) {
    const int*   z  = (const int*)  d_in[0];
    const float* X  = (const float*)d_in[1];
    const float* W1 = (const float*)d_in[2];
    const float* B1 = (const float*)d_in[3];
    const float* W2 = (const float*)d_in[4];
    const float* B2 = (const float*)d_in[5];
    float* out = (float*)d_out;
    int nAtoms = in_sizes[0];

    char* ws = (char*)d_ws;
    size_t off = 0;
    char* W1s      = ws + off;         off += (size_t)N_ELEM * ESTRIDE;  // 332800
    int* perm      = (int*)(ws + off); off += (size_t)nAtoms * 4;
    int* counts    = (int*)(ws + off); off += 32;
    int* cursorRel = (int*)(ws + off); off += 32;

    hipMemsetAsync(counts, 0, 64, stream);   // counts + cursorRel

    int hb = (nAtoms + 255) / 256;
    prep_hist_kernel<<<85 + hb, 256, 0, stream>>>(W1, B1, W2, W1s, z, nAtoms, counts);
    scatter_kernel<<<hb, 256, 0, stream>>>(z, nAtoms, counts, cursorRel, perm);
    mlp_kernel<<<NBLK, 256, 0, stream>>>(X, W1s, B2, perm, counts, out);
}

// Round 15
// 72.020 us; speedup vs baseline: 1.1493x; 1.0325x over previous
//
#include <hip/hip_runtime.h>
#include <hip/hip_bf16.h>

#define N_IN    256
#define N_HID   128
#define N_ELEM  5
#define NBLK    512                 // blocks; 2 per CU (65.5KB LDS each)
#define ESTRIDE 66560               // per-expert image: 65536 frag + 1024 params

typedef __attribute__((ext_vector_type(8))) short  short8;
typedef __attribute__((ext_vector_type(4))) short  short4v;
typedef __attribute__((ext_vector_type(4))) float  float4v;

__device__ __forceinline__ int expert_of(int z) {
    return (z == 1) ? 0 : (z == 6) ? 1 : (z == 7) ? 2 : (z == 8) ? 3 : 4;
}
__device__ __forceinline__ short f2bf(float f) {
    union { float f; unsigned u; } c; c.f = f;
    unsigned r = (c.u + 0x7fffu + ((c.u >> 16) & 1u)) >> 16;
    return (short)r;
}

#define AS3 __attribute__((address_space(3)))
#define GLOAD_LDS16(gsrc, ldst) \
    __builtin_amdgcn_global_load_lds((const __attribute__((address_space(1))) void*)(gsrc), \
                                     (AS3 void*)(ldst), 16, 0, 0)
__device__ __forceinline__ unsigned lds_off(const void* p) {
    return (unsigned)(size_t)(AS3 const char*)p;
}

#define DSR128(dst, a) asm volatile("ds_read_b128 %0, %1" : "=v"(dst) : "v"(a))
#define LGKM0 do { asm volatile("s_waitcnt lgkmcnt(0)" ::: "memory"); \
                   __builtin_amdgcn_sched_barrier(0); } while (0)
#define WAITV0 do { asm volatile("s_waitcnt vmcnt(0)" ::: "memory"); \
                    __builtin_amdgcn_sched_barrier(0); } while (0)

// ---------------- fused prep (swizzled W1 frag image + params) + histogram ----
// frag[slot=n*8+kk][lane] (16B) = bf16x8 of W1[e][n*16+(lane&15)][kk*32+(lane>>4)*8..]
// params @65536: b1[128] fp32, then w2[128] fp32.  (proven R9/R10/R14)
__global__ void prep_hist_kernel(const float* __restrict__ W1, const float* __restrict__ B1f,
                                 const float* __restrict__ W2f, char* __restrict__ W1s,
                                 const int* __restrict__ z, int n, int* __restrict__ counts) {
    if (blockIdx.x < 85) {
        int idx = blockIdx.x * 256 + threadIdx.x;
        if (idx < 20480) {
            int e = idx >> 12, rem = idx & 4095;
            int slot = rem >> 6, lane = rem & 63;
            int nrow = (slot >> 3) * 16 + (lane & 15);
            int k0 = (slot & 7) * 32 + (lane >> 4) * 8;
            const float* src = W1 + ((size_t)(e * N_HID + nrow) * N_IN + k0);
            float4v f0 = *(const float4v*)src;
            float4v f1 = *(const float4v*)(src + 4);
            short8 s;
            s[0] = f2bf(f0[0]); s[1] = f2bf(f0[1]); s[2] = f2bf(f0[2]); s[3] = f2bf(f0[3]);
            s[4] = f2bf(f1[0]); s[5] = f2bf(f1[1]); s[6] = f2bf(f1[2]); s[7] = f2bf(f1[3]);
            *(short8*)(W1s + (size_t)e * ESTRIDE + slot * 1024 + lane * 16) = s;
        } else {
            int idx2 = idx - 20480;              // < 1280
            int e = idx2 >> 8, i = idx2 & 255;
            float* dst = (float*)(W1s + (size_t)e * ESTRIDE + 65536);
            if (i < 128) dst[i] = B1f[e * N_HID + i];
            else         dst[128 + (i - 128)] = W2f[e * N_HID + (i - 128)];
        }
        return;
    }
    __shared__ int cnt[N_ELEM];
    if (threadIdx.x < N_ELEM) cnt[threadIdx.x] = 0;
    __syncthreads();
    int i = (blockIdx.x - 85) * blockDim.x + threadIdx.x;
    if (i < n) atomicAdd(&cnt[expert_of(z[i])], 1);
    __syncthreads();
    if (threadIdx.x < N_ELEM && cnt[threadIdx.x]) atomicAdd(&counts[threadIdx.x], cnt[threadIdx.x]);
}

// ---------------- scatter (computes prefix from counts in-block) ---------------
__global__ void scatter_kernel(const int* __restrict__ z, int n,
                               const int* __restrict__ counts,
                               int* __restrict__ cursorRel, int* __restrict__ perm) {
    __shared__ int cnt[N_ELEM], cur[N_ELEM], base[N_ELEM];
    int tid = threadIdx.x;
    if (tid < N_ELEM) { cnt[tid] = 0; cur[tid] = 0; }
    __syncthreads();
    int i = blockIdx.x * blockDim.x + tid;
    int e = -1;
    if (i < n) { e = expert_of(z[i]); atomicAdd(&cnt[e], 1); }
    __syncthreads();
    if (tid < N_ELEM) {
        int pfx = 0;
        for (int k = 0; k < tid; ++k) pfx += counts[k];
        base[tid] = cnt[tid] ? pfx + atomicAdd(&cursorRel[tid], cnt[tid]) : 0;
    }
    __syncthreads();
    if (e >= 0) {
        int r = atomicAdd(&cur[e], 1);
        perm[base[e] + r] = i;
    }
}

// ---------------- mlp: expert-uniform blocks, shared 64KB B, interleaved pipe --
// R14 structure, with the A pipeline refined: cvt moved into the K-loop at
// per-kk granularity; each rawA pair is reissued for tile s+1 right after its
// cvt. Flight time per load = ~1 full tile (uniform); outstanding vmem holds
// at 16/wave (no sawtooth). abf is a single short8 (VGPR ~170).
__launch_bounds__(256, 2)
__global__ void mlp_kernel(const float* __restrict__ X, const char* __restrict__ W1s,
                           const float* __restrict__ B2f, const int* __restrict__ perm,
                           const int* __restrict__ counts, float* __restrict__ out) {
    __shared__ char Bs[65536];              // one expert's full fragment image

    int lane = threadIdx.x & 63;
    int w    = threadIdx.x >> 6;
    int am   = lane & 15, g = lane >> 4;

    // ---- per-expert tables (uniform across all blocks)
    int cntv[N_ELEM], so[N_ELEM], ns[N_ELEM];
    int nSub = 0, acc0 = 0;
#pragma unroll
    for (int e = 0; e < N_ELEM; ++e) {
        cntv[e] = counts[e];
        so[e] = acc0; acc0 += cntv[e];
        ns[e] = (cntv[e] + 15) >> 4;
        nSub += ns[e];
    }
    // proportional block allocation (largest-floor + round-robin extras)
    int blk[N_ELEM], tot = 0;
#pragma unroll
    for (int e = 0; e < N_ELEM; ++e) {
        blk[e] = (int)(((long long)NBLK * ns[e]) / nSub);
        tot += blk[e];
    }
    int rem = NBLK - tot;                    // 0..4
#pragma unroll
    for (int e = 0; e < N_ELEM; ++e)
        if (rem > 0 && ns[e] > 0) { blk[e]++; rem--; }
    while (rem > 0) { blk[0]++; rem--; }     // safety (unreachable in practice)
#pragma unroll
    for (int e = 0; e < N_ELEM; ++e)
        if (ns[e] > 0 && blk[e] == 0) {      // safety: guarantee >=1 block
            int m = 0;
            for (int j = 1; j < N_ELEM; ++j) if (blk[j] > blk[m]) m = j;
            blk[m]--; blk[e]++;
        }
    int bp1 = blk[0], bp2 = bp1 + blk[1], bp3 = bp2 + blk[2], bp4 = bp3 + blk[3];

    int b = blockIdx.x;
    int e = (b >= bp1) + (b >= bp2) + (b >= bp3) + (b >= bp4);
    int bloc = b - ((e == 0) ? 0 : (e == 1) ? bp1 : (e == 2) ? bp2 : (e == 3) ? bp3 : bp4);
    int BE = blk[e], NE = ns[e];
    int soE = so[e], ctE = cntv[e];

    // ---- cooperative B image load: ALL waves, before any divergent exit
    const char* img = W1s + (size_t)e * ESTRIDE;
    {
        const char* wsrc = img + w * 16384 + lane * 16;
        char* wdst = Bs + w * 16384;
#pragma unroll
        for (int i = 0; i < 16; ++i)
            GLOAD_LDS16(wsrc + i * 1024, wdst + i * 1024);
    }
    WAITV0;
    __syncthreads();                         // B image complete for all waves

    // ---- per-wave subtile range (expert-local indices)
    int qe = (BE > 0) ? NE / BE : 0, re = (BE > 0) ? NE % BE : 0;
    int tb0 = bloc * qe + min(bloc, re);
    int tb1 = tb0 + qe + (bloc < re ? 1 : 0);
    int L = tb1 - tb0;
    int qw = L >> 2, rw = L & 3;
    int s0 = tb0 + w * qw + min(w, rw);
    int s1 = s0 + qw + (w < rw ? 1 : 0);
    if (s0 >= s1) return;                    // after the one barrier: safe

    unsigned BOFF = lds_off(Bs);
    int lastA = soE + ctE - 1;

    // params (tiny, L2-resident)
    const float* prm = (const float*)(img + 65536);
    float b1c[8], w2c[8];
#pragma unroll
    for (int n = 0; n < 8; ++n) {
        b1c[n] = prm[n * 16 + am];
        w2c[n] = prm[128 + n * 16 + am];
    }
    float b2v = B2f[e];

#define ROWSOF(s_) min(16, ctE - (s_) * 16)
#define GIDOF(s_) perm[min(soE + (s_) * 16 + am, lastA)]

    // ---- prologue: full 16-load burst for tile s0 only
    int rowsC = ROWSOF(s0);
    int gidC = GIDOF(s0);
    float4v rawA[16];
    {
        const float* base0 = X + ((size_t)(unsigned)gidC << 8) + g * 8;
#pragma unroll
        for (int kk = 0; kk < 8; ++kk) {
            rawA[2 * kk]     = *(const float4v*)(base0 + kk * 32);
            rawA[2 * kk + 1] = *(const float4v*)(base0 + kk * 32 + 4);
        }
    }
    int rowsN = rowsC, gidN = gidC;
    if (s0 + 1 < s1) { rowsN = ROWSOF(s0 + 1); gidN = GIDOF(s0 + 1); }

    for (int s = s0; s < s1; ++s) {
        bool pf = (s + 1 < s1);
        const float* baseN = X + ((size_t)(unsigned)gidN << 8) + g * 8;

        // ---- K-loop with interleaved cvt + reissue (uniform flight time)
        float4v acc[8] = {};
#pragma unroll
        for (int kk = 0; kk < 8; ++kk) {
            // issue B ds_reads first: they fly during the cvt's vmcnt stall
            short8 bpre[8];
#pragma unroll
            for (int n = 0; n < 8; ++n)
                DSR128(bpre[n], BOFF + (unsigned)((n * 8 + kk) * 1024 + lane * 16));
            // cvt tile-s pair (compiler inserts counted vmcnt wait)
            short8 abf;
            {
                float4v f0 = rawA[2 * kk], f1 = rawA[2 * kk + 1];
                union { __hip_bfloat162 h[4]; short8 v; } u;
                u.h[0] = __float22bfloat162_rn({f0[0], f0[1]});
                u.h[1] = __float22bfloat162_rn({f0[2], f0[3]});
                u.h[2] = __float22bfloat162_rn({f1[0], f1[1]});
                u.h[3] = __float22bfloat162_rn({f1[2], f1[3]});
                abf = u.v;
            }
            // reissue the freed pair for tile s+1 (stays in flight ~1 tile)
            if (pf) {
                rawA[2 * kk]     = *(const float4v*)(baseN + kk * 32);
                rawA[2 * kk + 1] = *(const float4v*)(baseN + kk * 32 + 4);
            }
            LGKM0;          // B-frags ready (count-independent, rule 18)
#pragma unroll
            for (int n = 0; n < 8; ++n)
                acc[n] = __builtin_amdgcn_mfma_f32_16x16x32_bf16(
                    abf, bpre[n], acc[n], 0, 0, 0);
        }

        // ---- epilogue: bias + silu + dot(w2), butterfly over 16 am-lanes
        float pv0 = 0, pv1 = 0, pv2 = 0, pv3 = 0;
#pragma unroll
        for (int n = 0; n < 8; ++n) {
            float v0 = acc[n][0] + b1c[n]; v0 = v0 / (1.0f + __expf(-v0));
            float v1 = acc[n][1] + b1c[n]; v1 = v1 / (1.0f + __expf(-v1));
            float v2 = acc[n][2] + b1c[n]; v2 = v2 / (1.0f + __expf(-v2));
            float v3 = acc[n][3] + b1c[n]; v3 = v3 / (1.0f + __expf(-v3));
            pv0 += v0 * w2c[n]; pv1 += v1 * w2c[n];
            pv2 += v2 * w2c[n]; pv3 += v3 * w2c[n];
        }
#pragma unroll
        for (int sh = 1; sh <= 8; sh <<= 1) {
            pv0 += __shfl_xor(pv0, sh, 64);
            pv1 += __shfl_xor(pv1, sh, 64);
            pv2 += __shfl_xor(pv2, sh, 64);
            pv3 += __shfl_xor(pv3, sh, 64);
        }
        float val = (am == 0) ? pv0 : (am == 1) ? pv1 : (am == 2) ? pv2 : pv3;
        int tgt = __shfl(gidC, g * 4 + am, 64);
        if (am < 4 && g * 4 + am < rowsC) out[tgt] = val + b2v;

        // shift pipeline state; fetch gid for s+2
        rowsC = rowsN; gidC = gidN;
        if (s + 2 < s1) { rowsN = ROWSOF(s + 2); gidN = GIDOF(s + 2); }
    }
#undef ROWSOF
#undef GIDOF
}

// ---------------- launch -------------------------------------------------------
extern "C" void kernel_launch(void* const* d_in, const int* in_sizes, int n_in,
                              void* d_out, int out_size, void* d_ws, size_t ws_size,
                              hipStream_t stream) {
    const int*   z  = (const int*)  d_in[0];
    const float* X  = (const float*)d_in[1];
    const float* W1 = (const float*)d_in[2];
    const float* B1 = (const float*)d_in[3];
    const float* W2 = (const float*)d_in[4];
    const float* B2 = (const float*)d_in[5];
    float* out = (float*)d_out;
    int nAtoms = in_sizes[0];

    char* ws = (char*)d_ws;
    size_t off = 0;
    char* W1s      = ws + off;         off += (size_t)N_ELEM * ESTRIDE;  // 332800
    int* perm      = (int*)(ws + off); off += (size_t)nAtoms * 4;
    int* counts    = (int*)(ws + off); off += 32;
    int* cursorRel = (int*)(ws + off); off += 32;

    hipMemsetAsync(counts, 0, 64, stream);   // counts + cursorRel

    int hb = (nAtoms + 255) / 256;
    prep_hist_kernel<<<85 + hb, 256, 0, stream>>>(W1, B1, W2, W1s, z, nAtoms, counts);
    scatter_kernel<<<hb, 256, 0, stream>>>(z, nAtoms, counts, cursorRel, perm);
    mlp_kernel<<<NBLK, 256, 0, stream>>>(X, W1s, B2, perm, counts, out);
}